// Round 1
// baseline (129.219 us; speedup 1.0000x reference)
//
#include <hip/hip_runtime.h>

// hex pooling: out[i][c] = max_{k<7} x[hex_idx[i][k]][c]
// L = out_size / C rows, C = 512, K = 7.

__global__ void hex_pool_kernel(const float* __restrict__ x,
                                const int* __restrict__ idx,
                                float* __restrict__ out,
                                int L, int C4 /* C/4 */) {
    int tid = blockIdx.x * blockDim.x + threadIdx.x;
    int total = L * C4;
    if (tid >= total) return;

    int row = tid / C4;
    int col = tid - row * C4;

    const float4* __restrict__ x4 = reinterpret_cast<const float4*>(x);
    const long long ibase = (long long)row * 7;

    // k = 0
    {
        // init with first neighbor (no -inf sentinel needed: K >= 1)
    }
    int r0 = idx[ibase + 0];
    float4 m = x4[(long long)r0 * C4 + col];

#pragma unroll
    for (int k = 1; k < 7; ++k) {
        int r = idx[ibase + k];
        float4 v = x4[(long long)r * C4 + col];
        m.x = fmaxf(m.x, v.x);
        m.y = fmaxf(m.y, v.y);
        m.z = fmaxf(m.z, v.z);
        m.w = fmaxf(m.w, v.w);
    }

    reinterpret_cast<float4*>(out)[tid] = m;
}

extern "C" void kernel_launch(void* const* d_in, const int* in_sizes, int n_in,
                              void* d_out, int out_size, void* d_ws, size_t ws_size,
                              hipStream_t stream) {
    const float* x = (const float*)d_in[0];
    const int* idx = (const int*)d_in[1];
    float* out = (float*)d_out;

    const int K = 7;
    const int n = in_sizes[1] / K;        // 40962
    const int C = in_sizes[0] / n;        // 512
    const int C4 = C / 4;                 // 128
    const int L = out_size / C;           // 10242

    int total = L * C4;
    int block = 256;
    int grid = (total + block - 1) / block;
    hex_pool_kernel<<<grid, block, 0, stream>>>(x, idx, out, L, C4);
}

// Round 2
// 129.090 us; speedup vs baseline: 1.0010x; 1.0010x over previous
//
#include <hip/hip_runtime.h>

// hex pooling: out[i][c] = max_{k<7} x[hex_idx[i][k]][c]
// One block (128 threads) per output row; idx loads are block-uniform ->
// compiler emits scalar s_load for the 7 indices.

__global__ __launch_bounds__(128) void hex_pool_kernel(
        const float* __restrict__ x,
        const int* __restrict__ idx,
        float* __restrict__ out,
        int C4 /* C/4 = 128 */) {
    const int row = blockIdx.x;          // uniform
    const int col = threadIdx.x;         // 0..127, one float4 each

    const int* __restrict__ ib = idx + (long long)row * 7;
    // Uniform (blockIdx-only) addresses -> s_load into SGPRs.
    int r0 = ib[0], r1 = ib[1], r2 = ib[2], r3 = ib[3];
    int r4 = ib[4], r5 = ib[5], r6 = ib[6];

    const float4* __restrict__ x4 = reinterpret_cast<const float4*>(x);

    float4 v0 = x4[(long long)r0 * C4 + col];
    float4 v1 = x4[(long long)r1 * C4 + col];
    float4 v2 = x4[(long long)r2 * C4 + col];
    float4 v3 = x4[(long long)r3 * C4 + col];
    float4 v4 = x4[(long long)r4 * C4 + col];
    float4 v5 = x4[(long long)r5 * C4 + col];
    float4 v6 = x4[(long long)r6 * C4 + col];

    float4 m;
    m.x = fmaxf(fmaxf(fmaxf(v0.x, v1.x), fmaxf(v2.x, v3.x)),
                fmaxf(fmaxf(v4.x, v5.x), v6.x));
    m.y = fmaxf(fmaxf(fmaxf(v0.y, v1.y), fmaxf(v2.y, v3.y)),
                fmaxf(fmaxf(v4.y, v5.y), v6.y));
    m.z = fmaxf(fmaxf(fmaxf(v0.z, v1.z), fmaxf(v2.z, v3.z)),
                fmaxf(fmaxf(v4.z, v5.z), v6.z));
    m.w = fmaxf(fmaxf(fmaxf(v0.w, v1.w), fmaxf(v2.w, v3.w)),
                fmaxf(fmaxf(v4.w, v5.w), v6.w));

    reinterpret_cast<float4*>(out)[(long long)row * C4 + col] = m;
}

extern "C" void kernel_launch(void* const* d_in, const int* in_sizes, int n_in,
                              void* d_out, int out_size, void* d_ws, size_t ws_size,
                              hipStream_t stream) {
    const float* x = (const float*)d_in[0];
    const int* idx = (const int*)d_in[1];
    float* out = (float*)d_out;

    const int K = 7;
    const int n = in_sizes[1] / K;        // 40962
    const int C = in_sizes[0] / n;        // 512
    const int C4 = C / 4;                 // 128
    const int L = out_size / C;           // 10242

    hex_pool_kernel<<<L, C4, 0, stream>>>(x, idx, out, C4);
}